// Round 7
// baseline (192.479 us; speedup 1.0000x reference)
//
#include <hip/hip_runtime.h>
#include <cstdint>
#include <cstddef>

#define B_ 8
#define S_ 1024
#define E_ 1024
#define H_ 16
#define D_ 64
#define M_ (B_*S_)

typedef _Float16 f16;
typedef __attribute__((ext_vector_type(8))) _Float16 f16x8;
typedef __attribute__((ext_vector_type(4))) _Float16 f16x4;
typedef __attribute__((ext_vector_type(4))) float  f32x4;
typedef __attribute__((ext_vector_type(16))) float f32x16;
typedef __attribute__((ext_vector_type(4))) int    int4v;
typedef __attribute__((ext_vector_type(2))) int    int2v;
typedef __attribute__((ext_vector_type(2))) unsigned long long u64x2;

__device__ __forceinline__ f32x4 mfma16(f16x8 a, f16x8 b, f32x4 c) {
  return __builtin_amdgcn_mfma_f32_16x16x32_f16(a, b, c, 0, 0, 0);
}
__device__ __forceinline__ f32x16 mfma32(f16x8 a, f16x8 b, f32x16 c) {
  return __builtin_amdgcn_mfma_f32_32x32x16_f16(a, b, c, 0, 0, 0);
}
__device__ __forceinline__ void gll16(const f16* g, f16* l) {
  __builtin_amdgcn_global_load_lds(
      (const __attribute__((address_space(1))) void*)g,
      (__attribute__((address_space(3))) void*)l, 16, 0, 0);
}
__device__ __forceinline__ int pkrtz(float lo, float hi) {
  return __builtin_bit_cast(int, __builtin_amdgcn_cvt_pkrtz(lo, hi));
}
// Conflict-free LDS fragment read: rows are 128B (bank = f(col) only), so the
// 16B XOR swizzle alone floors at 4-way. The global data carries an 8B-half
// swap keyed on row-bit3 (written by the GEMM epilogue); reading as two b64
// at +sel8 / +sel8^8 spreads the colliding lanes 2-way (free).
__device__ __forceinline__ f16x8 rdpair(const f16* rowp, int L, int rsw, int sel8) {
  const char* p = (const char*)rowp + (((L ^ rsw) << 4));
  u64x2 t;
  t[0] = *(const unsigned long long*)(p + sel8);
  t[1] = *(const unsigned long long*)(p + (sel8 ^ 8));
  return __builtin_bit_cast(f16x8, t);
}

// ---------------------------------------------------------------------------
// X fp32 -> fp16 (single)
// ---------------------------------------------------------------------------
__global__ __launch_bounds__(256) void presplit_kernel(
    const float* __restrict__ X, f16* __restrict__ Xf) {
  size_t i = ((size_t)blockIdx.x * 256 + threadIdx.x) * 8;
  f32x4 v0 = *(const f32x4*)&X[i];
  f32x4 v1 = *(const f32x4*)&X[i + 4];
  f16x8 hv;
#pragma unroll
  for (int j = 0; j < 4; ++j) {
    hv[j] = (f16)v0[j];
    hv[j + 4] = (f16)v1[j];
  }
  *(f16x8*)&Xf[i] = hv;
}

// ---------------------------------------------------------------------------
// Transpose + convert weights -> single fp16, [f][e] layout.
// W_Q pre-scaled by log2(e) (softmax runs in exp2 domain).
// ---------------------------------------------------------------------------
__global__ __launch_bounds__(512) void wt_conv3_kernel(
    const float* __restrict__ Wq, const float* __restrict__ Wk,
    const float* __restrict__ Wv, f16* __restrict__ oq, f16* __restrict__ ok,
    f16* __restrict__ ov) {
  const float* W = blockIdx.z == 0 ? Wq : (blockIdx.z == 1 ? Wk : Wv);
  f16* o = blockIdx.z == 0 ? oq : (blockIdx.z == 1 ? ok : ov);
  const float scl = blockIdx.z == 0 ? 1.4426950408889634f : 1.0f;
  __shared__ float t[64][65];
  const int f0 = blockIdx.x * 64, e0 = blockIdx.y * 64;
  const int tx = threadIdx.x, ty = threadIdx.y;
#pragma unroll
  for (int j = 0; j < 8; ++j)
    t[ty + 8 * j][tx] = W[(size_t)(e0 + ty + 8 * j) * E_ + f0 + tx];
  __syncthreads();
#pragma unroll
  for (int j = 0; j < 8; ++j)
    o[(size_t)(f0 + ty + 8 * j) * E_ + e0 + tx] =
        (f16)(t[tx][ty + 8 * j] * scl);
}

// ---------------------------------------------------------------------------
// Fused single-term QKV GEMM: O = X(f16) * W(f16).
// Epilogue bakes the attention LDS anti-conflict swizzle into K and V^T:
//   K:   element d stored at d^4 when (s & 8)   (8B-half swap per row-bit3)
//   V^T: key s stored at s^4 when (d & 8)
// Q stays linear (attn reads Q straight to registers).
// ---------------------------------------------------------------------------
__global__ __launch_bounds__(256) void gemm_qkv_kernel(
    const f16* __restrict__ Xf,
    const f16* __restrict__ Wq, const f16* __restrict__ Wk,
    const f16* __restrict__ Wv,
    f16* __restrict__ Qh, f16* __restrict__ Ql,
    f16* __restrict__ Kh, f16* __restrict__ Kl, f16* __restrict__ Vt) {
  __shared__ f16 sA[128][64], sB[128][64];   // 32 KB
  const int bid = blockIdx.x;
  const int xcd = bid & 7, idx = bid >> 3;   // idx in [0,192)
  const int mb = xcd * 8 + idx / 24;         // [0,64)
  const int nb = idx % 24;
  const int z = nb >> 3;
  const int n0 = (nb & 7) * 128, m0 = mb * 128;
  const f16* __restrict__ Bt = z == 0 ? Wq : (z == 1 ? Wk : Wv);
  const int tid = threadIdx.x;
  const int lane = tid & 63, w = tid >> 6;
  const int wm = (w >> 1) * 64, wn = (w & 1) * 64;
  const int fr = lane & 15, fg = lane >> 4;
  f32x4 acc[4][4] = {};
  for (int k0 = 0; k0 < E_; k0 += 64) {
#pragma unroll
    for (int i = 0; i < 4; ++i) {
      int ci = tid + i * 256;
      int r = ci >> 3, cl = ci & 7;
      int cs = (cl ^ (r & 7)) * 8;       // pre-swizzled global source column
      gll16(Xf + (size_t)(m0 + r) * E_ + k0 + cs, &sA[0][0] + ci * 8);
      gll16(Bt + (size_t)(n0 + r) * E_ + k0 + cs, &sB[0][0] + ci * 8);
    }
    __syncthreads();
#pragma unroll
    for (int kh2 = 0; kh2 < 2; ++kh2) {
      f16x8 ah[4];
#pragma unroll
      for (int mi = 0; mi < 4; ++mi) {
        int rA = wm + mi * 16 + fr;
        ah[mi] = *(const f16x8*)&sA[rA][(((kh2 * 4 + fg) ^ (rA & 7))) * 8];
      }
#pragma unroll
      for (int ni = 0; ni < 4; ++ni) {
        int rB = wn + ni * 16 + fr;
        f16x8 bh = *(const f16x8*)&sB[rB][(((kh2 * 4 + fg) ^ (rB & 7))) * 8];
#pragma unroll
        for (int mi = 0; mi < 4; ++mi)
          acc[mi][ni] = mfma16(ah[mi], bh, acc[mi][ni]);
      }
    }
    __syncthreads();
  }
  if (z < 2) {
    f16* Oh = z == 0 ? Qh : Kh;
    f16* Ol = z == 0 ? Ql : Kl;
#pragma unroll
    for (int mi = 0; mi < 4; ++mi)
#pragma unroll
      for (int ni = 0; ni < 4; ++ni)
#pragma unroll
        for (int r = 0; r < 4; ++r) {
          int row = m0 + wm + mi * 16 + (lane >> 4) * 4 + r;
          int col = n0 + wn + ni * 16 + fr;
          float v = acc[mi][ni][r];
          int bb = row >> 10, s = row & 1023;
          int hd = col >> 6, d = col & 63;
          if (z == 1 && (s & 8)) d ^= 4;   // K: bake attn 8B-half swizzle
          size_t idx2 = ((size_t)(bb * H_ + hd) * S_ + s) * D_ + d;
          f16 hh = (f16)v;
          Oh[idx2] = hh;
          Ol[idx2] = (f16)(v - (float)hh);
        }
  } else {
#pragma unroll
    for (int mi = 0; mi < 4; ++mi)
#pragma unroll
      for (int ni = 0; ni < 4; ++ni) {
        int row = m0 + wm + mi * 16 + (lane >> 4) * 4;
        int col = n0 + wn + ni * 16 + fr;
        int bb = row >> 10, s = row & 1023;
        int hd = col >> 6, d = col & 63;
        if (d & 8) s ^= 4;                 // V^T: bake attn 8B-half swizzle
        f16x4 p;
#pragma unroll
        for (int r = 0; r < 4; ++r) p[r] = (f16)acc[mi][ni][r];
        *(f16x4*)&Vt[((size_t)(bb * H_ + hd) * D_ + d) * S_ + s] = p;
      }
  }
}

// ---------------------------------------------------------------------------
// Flash attention + ReLU.  Grid 512, 4 waves x 64 q (qf=2), 2 blocks/CU.
// - conflict-free LDS reads: 16B XOR swizzle + global-baked 8B-half swap,
//   fragments read as 2x ds_read_b64 (rdpair)
// - speculative softmax: p = exp2(s - m_run) BEFORE the max reduction (exps
//   schedule into the QK MFMA shadow); rescale by 1/pmax only when
//   __any(pmax > 2^11) (exact correction of p, l, O; m_run ratchets up)
// - V fragments read once, shared by both q-fragments (pf hoisted)
// ---------------------------------------------------------------------------
__global__ __launch_bounds__(256, 2) void attn_kernel(
    const f16* __restrict__ Qh, const f16* __restrict__ Ql,
    const f16* __restrict__ Kh, const f16* __restrict__ Kl,
    const f16* __restrict__ Vt, float* __restrict__ out) {
  __shared__ f16 sKh[2][64][64], sKl[2][64][64], sV[2][64][64];
  const int bid = blockIdx.x;
  const int idx = bid >> 3;                       // [0,64)
  const int bh = (bid & 7) * 16 + (idx >> 2);     // same XCD: 16 heads chunk
  const int qb = idx & 3;
  const int hd = bh & 15, bb = bh >> 4;
  const int tid = threadIdx.x;
  const int lane = tid & 63, w = tid >> 6;
  const int cq = lane & 31, h = lane >> 5;
  const int rsw = cq & 7;          // 16B-chunk XOR key (row&7)
  const int sel8 = cq & 8;         // 8B-half select (row bit3 * 8)
  const size_t base = (size_t)bh * (S_ * D_);
  const f16* Qh_p = Qh + base;
  const f16* Ql_p = Ql + base;
  const f16* Kh_p = Kh + base;
  const f16* Kl_p = Kl + base;
  const f16* Vt_p = Vt + base;
  const int q0 = qb * 256 + w * 64;

  f16x8 qh_[2][4], ql_[2][4];
#pragma unroll
  for (int qf = 0; qf < 2; ++qf)
#pragma unroll
    for (int ks = 0; ks < 4; ++ks) {
      size_t off = (size_t)(q0 + qf * 32 + cq) * D_ + ks * 16 + 8 * h;
      qh_[qf][ks] = *(const f16x8*)&Qh_p[off];
      ql_[qf][ks] = *(const f16x8*)&Ql_p[off];
    }

  // m_run init ~ +2 sigma of row max (log2 domain); speculative exp is then
  // finite on chunk 0 and the first trigger rescales exactly.
  float m_run[2] = {64.f, 64.f};
  float l_run[2] = {0.f, 0.f};
  f32x16 O[2][2] = {};

#define STAGE(buf, kb)                                                        \
  {                                                                           \
    _Pragma("unroll")                                                         \
    for (int half = 0; half < 2; ++half) {                                    \
      int ci = tid + half * 256;                                              \
      int row = ci >> 3, cl = ci & 7;                                         \
      int cs = cl ^ (row & 7);                                                \
      gll16(Kh_p + (size_t)((kb) + row) * D_ + cs * 8, &sKh[buf][0][0] + ci * 8); \
      gll16(Kl_p + (size_t)((kb) + row) * D_ + cs * 8, &sKl[buf][0][0] + ci * 8); \
      gll16(Vt_p + (size_t)row * S_ + (kb) + cs * 8, &sV[buf][0][0] + ci * 8);    \
    }                                                                         \
  }

  STAGE(0, 0);
  int cur = 0;
  for (int t = 0; t < 16; ++t) {
    __builtin_amdgcn_s_barrier();          // all waves done with buf cur^1
    if (t < 15) {
      STAGE(cur ^ 1, (t + 1) * 64);
      asm volatile("s_waitcnt vmcnt(6)" ::: "memory");
    } else {
      asm volatile("s_waitcnt vmcnt(0)" ::: "memory");
    }
    __builtin_amdgcn_sched_barrier(0);
    __builtin_amdgcn_s_barrier();          // staged chunk visible to all

    // ---- QK^T (swapped, 3-term, both qf share K fragments)
    f32x16 sc[2][2] = {};
    __builtin_amdgcn_s_setprio(1);
#pragma unroll
    for (int f = 0; f < 2; ++f) {
      const f16* rK  = &sKh[cur][f * 32 + cq][0];
      const f16* rKl = &sKl[cur][f * 32 + cq][0];
#pragma unroll
      for (int ks = 0; ks < 4; ++ks) {
        f16x8 kh = rdpair(rK,  2 * ks + h, rsw, sel8);
        f16x8 kl = rdpair(rKl, 2 * ks + h, rsw, sel8);
#pragma unroll
        for (int qf = 0; qf < 2; ++qf) {
          sc[qf][f] = mfma32(kh, qh_[qf][ks], sc[qf][f]);
          sc[qf][f] = mfma32(kl, qh_[qf][ks], sc[qf][f]);
          sc[qf][f] = mfma32(kh, ql_[qf][ks], sc[qf][f]);
        }
      }
    }
    __builtin_amdgcn_s_setprio(0);

    // ---- per qf: speculative-exp softmax -> P frags
    f16x8 pf[2][4];
#pragma unroll
    for (int qf = 0; qf < 2; ++qf) {
      // p = exp2(s - m_run): no dependence on this chunk's max
#pragma unroll
      for (int f = 0; f < 2; ++f)
#pragma unroll
        for (int r = 0; r < 16; ++r)
          sc[qf][f][r] = __builtin_amdgcn_exp2f(sc[qf][f][r] - m_run[qf]);
      // max tree on p (monotone in score)
      float t8[8];
#pragma unroll
      for (int i = 0; i < 8; ++i)
        t8[i] = fmaxf(fmaxf(sc[qf][0][i], sc[qf][0][i + 8]),
                      fmaxf(sc[qf][1][i], sc[qf][1][i + 8]));
      float pm = fmaxf(fmaxf(fmaxf(t8[0], t8[4]), fmaxf(t8[1], t8[5])),
                       fmaxf(fmaxf(t8[2], t8[6]), fmaxf(t8[3], t8[7])));
      pm = fmaxf(pm, __shfl_xor(pm, 32));
      if (__any(pm > 2048.f)) {            // defer-max trigger (rare)
        float scl = pm > 1.0f ? 1.0f / pm : 1.0f;
        m_run[qf] += pm > 1.0f ? __builtin_amdgcn_logf(pm) : 0.f;
        l_run[qf] *= scl;
#pragma unroll
        for (int f = 0; f < 2; ++f)
#pragma unroll
          for (int r = 0; r < 16; ++r) sc[qf][f][r] *= scl;
#pragma unroll
        for (int df = 0; df < 2; ++df)
#pragma unroll
          for (int i = 0; i < 16; ++i) O[qf][df][i] *= scl;
      }
      float rs0 = 0.f, rs1 = 0.f, rs2 = 0.f, rs3 = 0.f;
#pragma unroll
      for (int f = 0; f < 2; ++f)
#pragma unroll
        for (int r = 0; r < 16; ++r) {
          float p = sc[qf][f][r];
          if ((r & 3) == 0) rs0 += p;
          else if ((r & 3) == 1) rs1 += p;
          else if ((r & 3) == 2) rs2 += p;
          else rs3 += p;
        }
      float rs = (rs0 + rs1) + (rs2 + rs3);
      rs += __shfl_xor(rs, 32);
      l_run[qf] += rs;

      // P fragments in-register: pf[ks][j] = P[16ks+8h+j][cq]
#pragma unroll
      for (int f = 0; f < 2; ++f)
#pragma unroll
        for (int ksl = 0; ksl < 2; ++ksl) {
          int b0 = 8 * ksl;
          int a1 = pkrtz(sc[qf][f][b0 + 0], sc[qf][f][b0 + 1]);
          int b1 = pkrtz(sc[qf][f][b0 + 4], sc[qf][f][b0 + 5]);
          int2v r1 = __builtin_amdgcn_permlane32_swap(a1, b1, false, false);
          int a2 = pkrtz(sc[qf][f][b0 + 2], sc[qf][f][b0 + 3]);
          int b2 = pkrtz(sc[qf][f][b0 + 6], sc[qf][f][b0 + 7]);
          int2v r2 = __builtin_amdgcn_permlane32_swap(a2, b2, false, false);
          int4v wd;
          wd[0] = r1[0]; wd[1] = r2[0]; wd[2] = r1[1]; wd[3] = r2[1];
          pf[qf][2 * f + ksl] = __builtin_bit_cast(f16x8, wd);
        }
    }

    // ---- PV: V fragments read once, used by both qf
    __builtin_amdgcn_s_setprio(1);
#pragma unroll
    for (int ks = 0; ks < 4; ++ks) {
#pragma unroll
      for (int df = 0; df < 2; ++df) {
        f16x8 vf = rdpair(&sV[cur][df * 32 + cq][0], 2 * ks + h, rsw, sel8);
        O[0][df] = mfma32(vf, pf[0][ks], O[0][df]);
        O[1][df] = mfma32(vf, pf[1][ks], O[1][df]);
      }
    }
    __builtin_amdgcn_s_setprio(0);
    cur ^= 1;
  }

  // ---- epilogue: relu(O/l) -> fp32 [B,S,E]
#pragma unroll
  for (int qf = 0; qf < 2; ++qf) {
    float inv = 1.0f / l_run[qf];
    int s = q0 + qf * 32 + cq;
    float* orow = out + ((size_t)bb * S_ + s) * E_ + hd * 64;
#pragma unroll
    for (int df = 0; df < 2; ++df)
#pragma unroll
      for (int g = 0; g < 4; ++g) {
        f32x4 vv;
#pragma unroll
        for (int j = 0; j < 4; ++j)
          vv[j] = fmaxf(O[qf][df][4 * g + j] * inv, 0.f);
        *(f32x4*)&orow[df * 32 + 8 * g + 4 * h] = vv;
      }
  }
}

// ---------------------------------------------------------------------------
// Launcher. Workspace ~102 MB:
//  Wq,Wk,Wv 3x2MB @0; Xf @6M; Qh @22M; Ql @38M; Kh @54M; Kl @70M; Vt @86M
// ---------------------------------------------------------------------------
extern "C" void kernel_launch(void* const* d_in, const int* in_sizes, int n_in,
                              void* d_out, int out_size, void* d_ws, size_t ws_size,
                              hipStream_t stream) {
  const float* X  = (const float*)d_in[0];
  const float* Wq = (const float*)d_in[1];
  const float* Wk = (const float*)d_in[2];
  const float* Wv = (const float*)d_in[3];
  float* out = (float*)d_out;
  char* ws = (char*)d_ws;

  const size_t WSZ = (size_t)E_ * E_ * sizeof(f16);   // 2 MB
  const size_t QSZ = (size_t)M_ * E_ * sizeof(f16);   // 16 MB
  f16* Wqf = (f16*)(ws);
  f16* Wkf = (f16*)(ws + WSZ);
  f16* Wvf = (f16*)(ws + 2 * WSZ);
  char* p = ws + 3 * WSZ;
  f16* Xf = (f16*)(p);
  f16* Qh = (f16*)(p + QSZ);
  f16* Ql = (f16*)(p + 2 * QSZ);
  f16* Kh = (f16*)(p + 3 * QSZ);
  f16* Kl = (f16*)(p + 4 * QSZ);
  f16* Vt = (f16*)(p + 5 * QSZ);

  presplit_kernel<<<4096, 256, 0, stream>>>(X, Xf);
  wt_conv3_kernel<<<dim3(16, 16, 3), dim3(64, 8), 0, stream>>>(
      Wq, Wk, Wv, Wqf, Wkf, Wvf);

  gemm_qkv_kernel<<<1536, 256, 0, stream>>>(
      Xf, Wqf, Wkf, Wvf, Qh, Ql, Kh, Kl, Vt);

  attn_kernel<<<512, 256, 0, stream>>>(Qh, Ql, Kh, Kl, Vt, out);
}

// Round 8
// 159.159 us; speedup vs baseline: 1.2094x; 1.2094x over previous
//
#include <hip/hip_runtime.h>
#include <cstdint>
#include <cstddef>

#define B_ 8
#define S_ 1024
#define E_ 1024
#define H_ 16
#define D_ 64
#define M_ (B_*S_)

typedef _Float16 f16;
typedef __attribute__((ext_vector_type(8))) _Float16 f16x8;
typedef __attribute__((ext_vector_type(4))) _Float16 f16x4;
typedef __attribute__((ext_vector_type(4))) float  f32x4;
typedef __attribute__((ext_vector_type(16))) float f32x16;
typedef __attribute__((ext_vector_type(4))) int    int4v;
typedef __attribute__((ext_vector_type(2))) int    int2v;

__device__ __forceinline__ f32x4 mfma16(f16x8 a, f16x8 b, f32x4 c) {
  return __builtin_amdgcn_mfma_f32_16x16x32_f16(a, b, c, 0, 0, 0);
}
__device__ __forceinline__ f32x16 mfma32(f16x8 a, f16x8 b, f32x16 c) {
  return __builtin_amdgcn_mfma_f32_32x32x16_f16(a, b, c, 0, 0, 0);
}
__device__ __forceinline__ void gll16(const f16* g, f16* l) {
  __builtin_amdgcn_global_load_lds(
      (const __attribute__((address_space(1))) void*)g,
      (__attribute__((address_space(3))) void*)l, 16, 0, 0);
}
__device__ __forceinline__ int pkrtz(float lo, float hi) {
  return __builtin_bit_cast(int, __builtin_amdgcn_cvt_pkrtz(lo, hi));
}

// ---------------------------------------------------------------------------
// X fp32 -> fp16
// ---------------------------------------------------------------------------
__global__ __launch_bounds__(256) void presplit_kernel(
    const float* __restrict__ X, f16* __restrict__ Xf) {
  size_t i = ((size_t)blockIdx.x * 256 + threadIdx.x) * 8;
  f32x4 v0 = *(const f32x4*)&X[i];
  f32x4 v1 = *(const f32x4*)&X[i + 4];
  f16x8 hv;
#pragma unroll
  for (int j = 0; j < 4; ++j) {
    hv[j] = (f16)v0[j];
    hv[j + 4] = (f16)v1[j];
  }
  *(f16x8*)&Xf[i] = hv;
}

// ---------------------------------------------------------------------------
// Transpose + convert weights -> single fp16, [f][e] layout.
// W_Q pre-scaled by log2(e) (softmax runs in exp2 domain).
// ---------------------------------------------------------------------------
__global__ __launch_bounds__(512) void wt_conv3_kernel(
    const float* __restrict__ Wq, const float* __restrict__ Wk,
    const float* __restrict__ Wv, f16* __restrict__ oq, f16* __restrict__ ok,
    f16* __restrict__ ov) {
  const float* W = blockIdx.z == 0 ? Wq : (blockIdx.z == 1 ? Wk : Wv);
  f16* o = blockIdx.z == 0 ? oq : (blockIdx.z == 1 ? ok : ov);
  const float scl = blockIdx.z == 0 ? 1.4426950408889634f : 1.0f;
  __shared__ float t[64][65];
  const int f0 = blockIdx.x * 64, e0 = blockIdx.y * 64;
  const int tx = threadIdx.x, ty = threadIdx.y;
#pragma unroll
  for (int j = 0; j < 8; ++j)
    t[ty + 8 * j][tx] = W[(size_t)(e0 + ty + 8 * j) * E_ + f0 + tx];
  __syncthreads();
#pragma unroll
  for (int j = 0; j < 8; ++j)
    o[(size_t)(f0 + ty + 8 * j) * E_ + e0 + tx] =
        (f16)(t[tx][ty + 8 * j] * scl);
}

// ---------------------------------------------------------------------------
// Fused QKV GEMM: O = X(f16) * W(f16).
// z: 0-7 = Q (hi/lo fp16 out, log2e-scaled), 8-15 = K (single fp16),
//    16-23 = V (single fp16, transposed [B,H,D,S]).
// XCD-chunked block swizzle; BM=BN=128, BK=64, XOR-swizzled LDS via
// pre-swizzled global source. Plain __launch_bounds__(256): a min-waves
// clamp spills the 64-reg accumulator (round-4: 1 GB scratch fetch).
// ---------------------------------------------------------------------------
__global__ __launch_bounds__(256) void gemm_qkv_kernel(
    const f16* __restrict__ Xf,
    const f16* __restrict__ Wq, const f16* __restrict__ Wk,
    const f16* __restrict__ Wv,
    f16* __restrict__ Qh, f16* __restrict__ Ql,
    f16* __restrict__ Kf, f16* __restrict__ Vt) {
  __shared__ f16 sA[128][64], sB[128][64];   // 32 KB
  const int bid = blockIdx.x;
  const int xcd = bid & 7, idx = bid >> 3;   // idx in [0,192)
  const int mb = xcd * 8 + idx / 24;         // [0,64)
  const int nb = idx % 24;
  const int z = nb >> 3;
  const int n0 = (nb & 7) * 128, m0 = mb * 128;
  const f16* __restrict__ Bt = z == 0 ? Wq : (z == 1 ? Wk : Wv);
  const int tid = threadIdx.x;
  const int lane = tid & 63, w = tid >> 6;
  const int wm = (w >> 1) * 64, wn = (w & 1) * 64;
  const int fr = lane & 15, fg = lane >> 4;
  f32x4 acc[4][4] = {};
  for (int k0 = 0; k0 < E_; k0 += 64) {
#pragma unroll
    for (int i = 0; i < 4; ++i) {
      int ci = tid + i * 256;
      int r = ci >> 3, cl = ci & 7;
      int cs = (cl ^ (r & 7)) * 8;       // pre-swizzled global source column
      gll16(Xf + (size_t)(m0 + r) * E_ + k0 + cs, &sA[0][0] + ci * 8);
      gll16(Bt + (size_t)(n0 + r) * E_ + k0 + cs, &sB[0][0] + ci * 8);
    }
    __syncthreads();
#pragma unroll
    for (int kh2 = 0; kh2 < 2; ++kh2) {
      f16x8 ah[4];
#pragma unroll
      for (int mi = 0; mi < 4; ++mi) {
        int rA = wm + mi * 16 + fr;
        ah[mi] = *(const f16x8*)&sA[rA][(((kh2 * 4 + fg) ^ (rA & 7))) * 8];
      }
#pragma unroll
      for (int ni = 0; ni < 4; ++ni) {
        int rB = wn + ni * 16 + fr;
        f16x8 bh = *(const f16x8*)&sB[rB][(((kh2 * 4 + fg) ^ (rB & 7))) * 8];
#pragma unroll
        for (int mi = 0; mi < 4; ++mi)
          acc[mi][ni] = mfma16(ah[mi], bh, acc[mi][ni]);
      }
    }
    __syncthreads();
  }
  if (z == 0) {
#pragma unroll
    for (int mi = 0; mi < 4; ++mi)
#pragma unroll
      for (int ni = 0; ni < 4; ++ni)
#pragma unroll
        for (int r = 0; r < 4; ++r) {
          int row = m0 + wm + mi * 16 + (lane >> 4) * 4 + r;
          int col = n0 + wn + ni * 16 + fr;
          float v = acc[mi][ni][r];
          int bb = row >> 10, s = row & 1023;
          int hd = col >> 6, d = col & 63;
          size_t idx2 = ((size_t)(bb * H_ + hd) * S_ + s) * D_ + d;
          f16 hh = (f16)v;
          Qh[idx2] = hh;
          Ql[idx2] = (f16)(v - (float)hh);
        }
  } else if (z == 1) {
#pragma unroll
    for (int mi = 0; mi < 4; ++mi)
#pragma unroll
      for (int ni = 0; ni < 4; ++ni)
#pragma unroll
        for (int r = 0; r < 4; ++r) {
          int row = m0 + wm + mi * 16 + (lane >> 4) * 4 + r;
          int col = n0 + wn + ni * 16 + fr;
          int bb = row >> 10, s = row & 1023;
          int hd = col >> 6, d = col & 63;
          Kf[((size_t)(bb * H_ + hd) * S_ + s) * D_ + d] = (f16)acc[mi][ni][r];
        }
  } else {
#pragma unroll
    for (int mi = 0; mi < 4; ++mi)
#pragma unroll
      for (int ni = 0; ni < 4; ++ni) {
        int row = m0 + wm + mi * 16 + (lane >> 4) * 4;
        int col = n0 + wn + ni * 16 + fr;
        int bb = row >> 10, s = row & 1023;
        int hd = col >> 6, d = col & 63;
        f16x4 p;
#pragma unroll
        for (int r = 0; r < 4; ++r) p[r] = (f16)acc[mi][ni][r];
        *(f16x4*)&Vt[((size_t)(bb * H_ + hd) * D_ + d) * S_ + s] = p;
      }
  }
}

// ---------------------------------------------------------------------------
// Flash attention + ReLU.  Grid 512, 4 waves x 64 q, 2 blocks/CU.
// Software-pipelined: triple-buffered K/V LDS, ONE barrier per chunk;
// per iter: QK(t+1) [MFMA] ; STAGE(t+2) ; exps(t+1) [VALU] || PV(t) [MFMA].
// K single-fp16 (Q stays hi/lo in regs -> 2-term QK^T); sc MFMA C-init = -m
// (no subs); post-exp max-tree (v_max3-able) for the rare defer-rescale,
// applied AFTER PV(t) so history stays consistent.
// ---------------------------------------------------------------------------
__global__ __launch_bounds__(256, 2) void attn_kernel(
    const f16* __restrict__ Qh, const f16* __restrict__ Ql,
    const f16* __restrict__ Kf, const f16* __restrict__ Vt,
    float* __restrict__ out) {
  __shared__ f16 sK[3][64][64], sV[3][64][64];   // 48 KB
  const int bid = blockIdx.x;
  const int idx = bid >> 3;
  const int bh = (bid & 7) * 16 + (idx >> 2);    // same head group -> same XCD
  const int qb = idx & 3;
  const int hd = bh & 15, bb = bh >> 4;
  const int tid = threadIdx.x;
  const int lane = tid & 63, w = tid >> 6;
  const int cq = lane & 31, h = lane >> 5;
  const int rsw = cq & 7;
  const size_t base = (size_t)bh * (S_ * D_);
  const f16* Qh_p = Qh + base;
  const f16* Ql_p = Ql + base;
  const f16* Kf_p = Kf + base;
  const f16* Vt_p = Vt + base;
  const int q0 = qb * 256 + w * 64;

  f16x8 qh_[2][4], ql_[2][4];
#pragma unroll
  for (int qf = 0; qf < 2; ++qf)
#pragma unroll
    for (int ks = 0; ks < 4; ++ks) {
      size_t off = (size_t)(q0 + qf * 32 + cq) * D_ + ks * 16 + 8 * h;
      qh_[qf][ks] = *(const f16x8*)&Qh_p[off];
      ql_[qf][ks] = *(const f16x8*)&Ql_p[off];
    }

  float m_run[2], l_run[2];
  f32x16 O[2][2] = {};
  f16x8 pf[2][4];

#define STAGE(buf, kb)                                                        \
  {                                                                           \
    _Pragma("unroll")                                                         \
    for (int half = 0; half < 2; ++half) {                                    \
      int ci = tid + half * 256;                                              \
      int row = ci >> 3, cl = ci & 7;                                         \
      int cs = cl ^ (row & 7);                                                \
      gll16(Kf_p + (size_t)((kb) + row) * D_ + cs * 8, &sK[buf][0][0] + ci * 8); \
      gll16(Vt_p + (size_t)row * S_ + (kb) + cs * 8, &sV[buf][0][0] + ci * 8);   \
    }                                                                         \
  }

#define QKT(scv, bufi)                                                        \
  {                                                                           \
    _Pragma("unroll")                                                         \
    for (int f = 0; f < 2; ++f) {                                             \
      _Pragma("unroll")                                                       \
      for (int ks = 0; ks < 4; ++ks) {                                        \
        int cc = ((2 * ks + h) ^ rsw) * 8;                                    \
        f16x8 kv = *(const f16x8*)&sK[bufi][f * 32 + cq][cc];                 \
        _Pragma("unroll")                                                     \
        for (int qf = 0; qf < 2; ++qf) {                                      \
          scv[qf][f] = mfma32(kv, qh_[qf][ks], scv[qf][f]);                   \
          scv[qf][f] = mfma32(kv, ql_[qf][ks], scv[qf][f]);                   \
        }                                                                     \
      }                                                                       \
    }                                                                         \
  }

#define PVT(bufi)                                                             \
  {                                                                           \
    _Pragma("unroll")                                                         \
    for (int ks = 0; ks < 4; ++ks) {                                          \
      _Pragma("unroll")                                                       \
      for (int df = 0; df < 2; ++df) {                                        \
        int cc = ((2 * ks + h) ^ rsw) * 8;                                    \
        f16x8 vf = *(const f16x8*)&sV[bufi][df * 32 + cq][cc];                \
        O[0][df] = mfma32(vf, pf[0][ks], O[0][df]);                           \
        O[1][df] = mfma32(vf, pf[1][ks], O[1][df]);                           \
      }                                                                       \
    }                                                                         \
  }

#define PFBUILD(qf, scv)                                                      \
  {                                                                           \
    _Pragma("unroll")                                                         \
    for (int f = 0; f < 2; ++f) {                                             \
      _Pragma("unroll")                                                       \
      for (int ksl = 0; ksl < 2; ++ksl) {                                     \
        int b0 = 8 * ksl;                                                     \
        int a1 = pkrtz(scv[qf][f][b0 + 0], scv[qf][f][b0 + 1]);               \
        int b1 = pkrtz(scv[qf][f][b0 + 4], scv[qf][f][b0 + 5]);               \
        int2v r1 = __builtin_amdgcn_permlane32_swap(a1, b1, false, false);    \
        int a2 = pkrtz(scv[qf][f][b0 + 2], scv[qf][f][b0 + 3]);               \
        int b2 = pkrtz(scv[qf][f][b0 + 6], scv[qf][f][b0 + 7]);               \
        int2v r2 = __builtin_amdgcn_permlane32_swap(a2, b2, false, false);    \
        int4v wd;                                                             \
        wd[0] = r1[0]; wd[1] = r2[0]; wd[2] = r1[1]; wd[3] = r2[1];           \
        pf[qf][2 * f + ksl] = __builtin_bit_cast(f16x8, wd);                  \
      }                                                                       \
    }                                                                         \
  }

#define MAXTREE(pm, scv, qf)                                                  \
  {                                                                           \
    float t4[4];                                                              \
    _Pragma("unroll")                                                         \
    for (int i = 0; i < 4; ++i) {                                             \
      float a = fmaxf(fmaxf(scv[qf][0][i], scv[qf][0][i + 4]),                \
                      fmaxf(scv[qf][0][i + 8], scv[qf][0][i + 12]));          \
      float b = fmaxf(fmaxf(scv[qf][1][i], scv[qf][1][i + 4]),                \
                      fmaxf(scv[qf][1][i + 8], scv[qf][1][i + 12]));          \
      t4[i] = fmaxf(a, b);                                                    \
    }                                                                         \
    pm = fmaxf(fmaxf(t4[0], t4[1]), fmaxf(t4[2], t4[3]));                     \
    pm = fmaxf(pm, __shfl_xor(pm, 32));                                       \
  }

#define ROWSUM(rs, scv, qf)                                                   \
  {                                                                           \
    float rs0 = 0.f, rs1 = 0.f, rs2 = 0.f, rs3 = 0.f;                         \
    _Pragma("unroll")                                                         \
    for (int f = 0; f < 2; ++f) {                                             \
      _Pragma("unroll")                                                       \
      for (int r4 = 0; r4 < 4; ++r4) {                                        \
        rs0 += scv[qf][f][4 * r4 + 0];                                        \
        rs1 += scv[qf][f][4 * r4 + 1];                                        \
        rs2 += scv[qf][f][4 * r4 + 2];                                        \
        rs3 += scv[qf][f][4 * r4 + 3];                                        \
      }                                                                       \
    }                                                                         \
    rs = (rs0 + rs1) + (rs2 + rs3);                                           \
    rs += __shfl_xor(rs, 32);                                                 \
  }

  // ---- prologue: chunk 0 (exact max path)
  int bc = 0, bn = 1, bs = 2;
  STAGE(0, 0);
  asm volatile("s_waitcnt vmcnt(0)" ::: "memory");
  __builtin_amdgcn_sched_barrier(0);
  __builtin_amdgcn_s_barrier();
  STAGE(1, 64);
  {
    f32x16 sc[2][2] = {};
    QKT(sc, 0);
#pragma unroll
    for (int qf = 0; qf < 2; ++qf) {
      float pm;
      MAXTREE(pm, sc, qf);
      m_run[qf] = pm;
#pragma unroll
      for (int f = 0; f < 2; ++f)
#pragma unroll
        for (int r = 0; r < 16; ++r)
          sc[qf][f][r] = __builtin_amdgcn_exp2f(sc[qf][f][r] - pm);
      float rs;
      ROWSUM(rs, sc, qf);
      l_run[qf] = rs;
      PFBUILD(qf, sc);
    }
  }

  // ---- main pipeline: iter t does QK(t+1), STAGE(t+2), softmax(t+1), PV(t)
  for (int t = 0; t < 15; ++t) {
    asm volatile("s_waitcnt vmcnt(0)" ::: "memory");   // own STAGE(t+1) landed
    __builtin_amdgcn_sched_barrier(0);
    __builtin_amdgcn_s_barrier();                      // all waves' t+1 ready

    f32x16 sc[2][2];
#pragma unroll
    for (int qf = 0; qf < 2; ++qf)
#pragma unroll
      for (int f = 0; f < 2; ++f)
#pragma unroll
        for (int r = 0; r < 16; ++r) sc[qf][f][r] = -m_run[qf];
    __builtin_amdgcn_s_setprio(1);
    QKT(sc, bn);
    __builtin_amdgcn_s_setprio(0);
    if (t < 14) STAGE(bs, (t + 2) * 64);

    // speculative exp (vs running m); independent of PV(t)
#pragma unroll
    for (int qf = 0; qf < 2; ++qf)
#pragma unroll
      for (int f = 0; f < 2; ++f)
#pragma unroll
        for (int r = 0; r < 16; ++r)
          sc[qf][f][r] = __builtin_amdgcn_exp2f(sc[qf][f][r]);
    float pm0, pm1;
    MAXTREE(pm0, sc, 0);
    MAXTREE(pm1, sc, 1);
    bool trig = __any(fmaxf(pm0, pm1) > 2048.f);
    float scl[2] = {1.f, 1.f};
    if (trig) {
#pragma unroll
      for (int qf = 0; qf < 2; ++qf) {
        float pmx = fmaxf(qf == 0 ? pm0 : pm1, 1.0f);
        scl[qf] = 1.0f / pmx;
        m_run[qf] += __builtin_amdgcn_logf(pmx);
#pragma unroll
        for (int f = 0; f < 2; ++f)
#pragma unroll
          for (int r = 0; r < 16; ++r) sc[qf][f][r] *= scl[qf];
      }
    }

    // PV(t): consumes pf (chunk t, old scale) -> O is old-scale thru t
    __builtin_amdgcn_s_setprio(1);
    PVT(bc);
    __builtin_amdgcn_s_setprio(0);

    if (trig) {
#pragma unroll
      for (int qf = 0; qf < 2; ++qf) {
        l_run[qf] *= scl[qf];
#pragma unroll
        for (int df = 0; df < 2; ++df)
#pragma unroll
          for (int i = 0; i < 16; ++i) O[qf][df][i] *= scl[qf];
      }
    }
#pragma unroll
    for (int qf = 0; qf < 2; ++qf) {
      float rs;
      ROWSUM(rs, sc, qf);
      l_run[qf] += rs;
      PFBUILD(qf, sc);
    }
    int tmp = bc; bc = bn; bn = bs; bs = tmp;          // rotate buffers
  }
  // ---- last PV (chunk 15; synced at iter-14's barrier)
  PVT(bc);

  // ---- epilogue: relu(O/l) -> fp32 [B,S,E]
#pragma unroll
  for (int qf = 0; qf < 2; ++qf) {
    float inv = 1.0f / l_run[qf];
    int s = q0 + qf * 32 + cq;
    float* orow = out + ((size_t)bb * S_ + s) * E_ + hd * 64;
#pragma unroll
    for (int df = 0; df < 2; ++df)
#pragma unroll
      for (int g = 0; g < 4; ++g) {
        f32x4 vv;
#pragma unroll
        for (int j = 0; j < 4; ++j)
          vv[j] = fmaxf(O[qf][df][4 * g + j] * inv, 0.f);
        *(f32x4*)&orow[df * 32 + 8 * g + 4 * h] = vv;
      }
  }
}

// ---------------------------------------------------------------------------
// Launcher. Workspace ~86 MB:
//  Wq,Wk,Wv 3x2MB @0; Xf @6M; Qh @22M; Ql @38M; Kf @54M; Vt @70M
// ---------------------------------------------------------------------------
extern "C" void kernel_launch(void* const* d_in, const int* in_sizes, int n_in,
                              void* d_out, int out_size, void* d_ws, size_t ws_size,
                              hipStream_t stream) {
  const float* X  = (const float*)d_in[0];
  const float* Wq = (const float*)d_in[1];
  const float* Wk = (const float*)d_in[2];
  const float* Wv = (const float*)d_in[3];
  float* out = (float*)d_out;
  char* ws = (char*)d_ws;

  const size_t WSZ = (size_t)E_ * E_ * sizeof(f16);   // 2 MB
  const size_t QSZ = (size_t)M_ * E_ * sizeof(f16);   // 16 MB
  f16* Wqf = (f16*)(ws);
  f16* Wkf = (f16*)(ws + WSZ);
  f16* Wvf = (f16*)(ws + 2 * WSZ);
  char* p = ws + 3 * WSZ;
  f16* Xf = (f16*)(p);
  f16* Qh = (f16*)(p + QSZ);
  f16* Ql = (f16*)(p + 2 * QSZ);
  f16* Kf = (f16*)(p + 3 * QSZ);
  f16* Vt = (f16*)(p + 4 * QSZ);

  presplit_kernel<<<4096, 256, 0, stream>>>(X, Xf);
  wt_conv3_kernel<<<dim3(16, 16, 3), dim3(64, 8), 0, stream>>>(
      Wq, Wk, Wv, Wqf, Wkf, Wvf);

  gemm_qkv_kernel<<<1536, 256, 0, stream>>>(
      Xf, Wqf, Wkf, Wvf, Qh, Ql, Kf, Vt);

  attn_kernel<<<512, 256, 0, stream>>>(Qh, Ql, Kf, Vt, out);
}

// Round 9
// 146.967 us; speedup vs baseline: 1.3097x; 1.0830x over previous
//
#include <hip/hip_runtime.h>
#include <cstdint>
#include <cstddef>

#define B_ 8
#define S_ 1024
#define E_ 1024
#define H_ 16
#define D_ 64
#define M_ (B_*S_)

typedef _Float16 f16;
typedef __attribute__((ext_vector_type(8))) _Float16 f16x8;
typedef __attribute__((ext_vector_type(4))) _Float16 f16x4;
typedef __attribute__((ext_vector_type(4))) float  f32x4;
typedef __attribute__((ext_vector_type(16))) float f32x16;
typedef __attribute__((ext_vector_type(4))) int    int4v;
typedef __attribute__((ext_vector_type(2))) int    int2v;

__device__ __forceinline__ f32x4 mfma16(f16x8 a, f16x8 b, f32x4 c) {
  return __builtin_amdgcn_mfma_f32_16x16x32_f16(a, b, c, 0, 0, 0);
}
__device__ __forceinline__ f32x16 mfma32(f16x8 a, f16x8 b, f32x16 c) {
  return __builtin_amdgcn_mfma_f32_32x32x16_f16(a, b, c, 0, 0, 0);
}
__device__ __forceinline__ void gll16(const f16* g, f16* l) {
  __builtin_amdgcn_global_load_lds(
      (const __attribute__((address_space(1))) void*)g,
      (__attribute__((address_space(3))) void*)l, 16, 0, 0);
}
__device__ __forceinline__ int pkrtz(float lo, float hi) {
  return __builtin_bit_cast(int, __builtin_amdgcn_cvt_pkrtz(lo, hi));
}

// ---------------------------------------------------------------------------
// X fp32 -> fp16
// ---------------------------------------------------------------------------
__global__ __launch_bounds__(256) void presplit_kernel(
    const float* __restrict__ X, f16* __restrict__ Xf) {
  size_t i = ((size_t)blockIdx.x * 256 + threadIdx.x) * 8;
  f32x4 v0 = *(const f32x4*)&X[i];
  f32x4 v1 = *(const f32x4*)&X[i + 4];
  f16x8 hv;
#pragma unroll
  for (int j = 0; j < 4; ++j) {
    hv[j] = (f16)v0[j];
    hv[j + 4] = (f16)v1[j];
  }
  *(f16x8*)&Xf[i] = hv;
}

// ---------------------------------------------------------------------------
// Transpose + convert weights -> single fp16, [f][e] layout.
// W_Q pre-scaled by log2(e) (softmax runs in exp2 domain).
// ---------------------------------------------------------------------------
__global__ __launch_bounds__(512) void wt_conv3_kernel(
    const float* __restrict__ Wq, const float* __restrict__ Wk,
    const float* __restrict__ Wv, f16* __restrict__ oq, f16* __restrict__ ok,
    f16* __restrict__ ov) {
  const float* W = blockIdx.z == 0 ? Wq : (blockIdx.z == 1 ? Wk : Wv);
  f16* o = blockIdx.z == 0 ? oq : (blockIdx.z == 1 ? ok : ov);
  const float scl = blockIdx.z == 0 ? 1.4426950408889634f : 1.0f;
  __shared__ float t[64][65];
  const int f0 = blockIdx.x * 64, e0 = blockIdx.y * 64;
  const int tx = threadIdx.x, ty = threadIdx.y;
#pragma unroll
  for (int j = 0; j < 8; ++j)
    t[ty + 8 * j][tx] = W[(size_t)(e0 + ty + 8 * j) * E_ + f0 + tx];
  __syncthreads();
#pragma unroll
  for (int j = 0; j < 8; ++j)
    o[(size_t)(f0 + ty + 8 * j) * E_ + e0 + tx] =
        (f16)(t[tx][ty + 8 * j] * scl);
}

// ---------------------------------------------------------------------------
// Fused QKV GEMM: O = X(f16) * W(f16).  (unchanged from round 8: ~850 TF)
// z: 0-7 = Q (hi/lo fp16 out, log2e-scaled), 8-15 = K (single fp16),
//    16-23 = V (single fp16, transposed [B,H,D,S]).
// ---------------------------------------------------------------------------
__global__ __launch_bounds__(256) void gemm_qkv_kernel(
    const f16* __restrict__ Xf,
    const f16* __restrict__ Wq, const f16* __restrict__ Wk,
    const f16* __restrict__ Wv,
    f16* __restrict__ Qh, f16* __restrict__ Ql,
    f16* __restrict__ Kf, f16* __restrict__ Vt) {
  __shared__ f16 sA[128][64], sB[128][64];   // 32 KB
  const int bid = blockIdx.x;
  const int xcd = bid & 7, idx = bid >> 3;   // idx in [0,192)
  const int mb = xcd * 8 + idx / 24;         // [0,64)
  const int nb = idx % 24;
  const int z = nb >> 3;
  const int n0 = (nb & 7) * 128, m0 = mb * 128;
  const f16* __restrict__ Bt = z == 0 ? Wq : (z == 1 ? Wk : Wv);
  const int tid = threadIdx.x;
  const int lane = tid & 63, w = tid >> 6;
  const int wm = (w >> 1) * 64, wn = (w & 1) * 64;
  const int fr = lane & 15, fg = lane >> 4;
  f32x4 acc[4][4] = {};
  for (int k0 = 0; k0 < E_; k0 += 64) {
#pragma unroll
    for (int i = 0; i < 4; ++i) {
      int ci = tid + i * 256;
      int r = ci >> 3, cl = ci & 7;
      int cs = (cl ^ (r & 7)) * 8;       // pre-swizzled global source column
      gll16(Xf + (size_t)(m0 + r) * E_ + k0 + cs, &sA[0][0] + ci * 8);
      gll16(Bt + (size_t)(n0 + r) * E_ + k0 + cs, &sB[0][0] + ci * 8);
    }
    __syncthreads();
#pragma unroll
    for (int kh2 = 0; kh2 < 2; ++kh2) {
      f16x8 ah[4];
#pragma unroll
      for (int mi = 0; mi < 4; ++mi) {
        int rA = wm + mi * 16 + fr;
        ah[mi] = *(const f16x8*)&sA[rA][(((kh2 * 4 + fg) ^ (rA & 7))) * 8];
      }
#pragma unroll
      for (int ni = 0; ni < 4; ++ni) {
        int rB = wn + ni * 16 + fr;
        f16x8 bh = *(const f16x8*)&sB[rB][(((kh2 * 4 + fg) ^ (rB & 7))) * 8];
#pragma unroll
        for (int mi = 0; mi < 4; ++mi)
          acc[mi][ni] = mfma16(ah[mi], bh, acc[mi][ni]);
      }
    }
    __syncthreads();
  }
  if (z == 0) {
#pragma unroll
    for (int mi = 0; mi < 4; ++mi)
#pragma unroll
      for (int ni = 0; ni < 4; ++ni)
#pragma unroll
        for (int r = 0; r < 4; ++r) {
          int row = m0 + wm + mi * 16 + (lane >> 4) * 4 + r;
          int col = n0 + wn + ni * 16 + fr;
          float v = acc[mi][ni][r];
          int bb = row >> 10, s = row & 1023;
          int hd = col >> 6, d = col & 63;
          size_t idx2 = ((size_t)(bb * H_ + hd) * S_ + s) * D_ + d;
          f16 hh = (f16)v;
          Qh[idx2] = hh;
          Ql[idx2] = (f16)(v - (float)hh);
        }
  } else if (z == 1) {
#pragma unroll
    for (int mi = 0; mi < 4; ++mi)
#pragma unroll
      for (int ni = 0; ni < 4; ++ni)
#pragma unroll
        for (int r = 0; r < 4; ++r) {
          int row = m0 + wm + mi * 16 + (lane >> 4) * 4 + r;
          int col = n0 + wn + ni * 16 + fr;
          int bb = row >> 10, s = row & 1023;
          int hd = col >> 6, d = col & 63;
          Kf[((size_t)(bb * H_ + hd) * S_ + s) * D_ + d] = (f16)acc[mi][ni][r];
        }
  } else {
#pragma unroll
    for (int mi = 0; mi < 4; ++mi)
#pragma unroll
      for (int ni = 0; ni < 4; ++ni) {
        int row = m0 + wm + mi * 16 + (lane >> 4) * 4;
        int col = n0 + wn + ni * 16 + fr;
        int bb = row >> 10, s = row & 1023;
        int hd = col >> 6, d = col & 63;
        f16x4 p;
#pragma unroll
        for (int r = 0; r < 4; ++r) p[r] = (f16)acc[mi][ni][r];
        *(f16x4*)&Vt[((size_t)(bb * H_ + hd) * D_ + d) * S_ + s] = p;
      }
  }
}

// ---------------------------------------------------------------------------
// Flash attention + ReLU.  OCCUPANCY round: qf=1 (32 q/wave, 128 q/block),
// grid 1024, launch_bounds(256,3) -> ~125 total regs/wave, 3 blocks/CU
// (12 waves/CU, LDS 48KB x 3 = 144KB).  Round-8 evidence: duration pinned
// by issue stalls at 2 waves/SIMD (MfmaUtil+VALUBusy = 59%), work halving
// changed nothing -- so add waves, keep total work constant.
// Same software pipeline: triple-buffer, one barrier/chunk,
// QK(t+1) ; STAGE(t+2) ; spec-exp softmax(t+1) ; PV(t).
// XCD map: all 8 q-blocks of one (b,h) co-resident on one XCD.
// ---------------------------------------------------------------------------
__global__ __launch_bounds__(256, 3) void attn_kernel(
    const f16* __restrict__ Qh, const f16* __restrict__ Ql,
    const f16* __restrict__ Kf, const f16* __restrict__ Vt,
    float* __restrict__ out) {
  __shared__ f16 sK[3][64][64], sV[3][64][64];   // 48 KB
  const int bid = blockIdx.x;
  const int bh = (bid & 7) * 16 + (bid >> 6);    // 8 qb of one bh adjacent
  const int qb = (bid >> 3) & 7;
  const int hd = bh & 15, bb = bh >> 4;
  const int tid = threadIdx.x;
  const int lane = tid & 63, w = tid >> 6;
  const int cq = lane & 31, h = lane >> 5;
  const int rsw = cq & 7;
  const size_t base = (size_t)bh * (S_ * D_);
  const f16* Qh_p = Qh + base;
  const f16* Ql_p = Ql + base;
  const f16* Kf_p = Kf + base;
  const f16* Vt_p = Vt + base;
  const int q0 = qb * 128 + w * 32;

  f16x8 qh_[4], ql_[4];
#pragma unroll
  for (int ks = 0; ks < 4; ++ks) {
    size_t off = (size_t)(q0 + cq) * D_ + ks * 16 + 8 * h;
    qh_[ks] = *(const f16x8*)&Qh_p[off];
    ql_[ks] = *(const f16x8*)&Ql_p[off];
  }

  float m_run, l_run;
  f32x16 O[2] = {};
  f16x8 pf[4];

#define STAGE(buf, kb)                                                        \
  {                                                                           \
    _Pragma("unroll")                                                         \
    for (int half = 0; half < 2; ++half) {                                    \
      int ci = tid + half * 256;                                              \
      int row = ci >> 3, cl = ci & 7;                                         \
      int cs = cl ^ (row & 7);                                                \
      gll16(Kf_p + (size_t)((kb) + row) * D_ + cs * 8, &sK[buf][0][0] + ci * 8); \
      gll16(Vt_p + (size_t)row * S_ + (kb) + cs * 8, &sV[buf][0][0] + ci * 8);   \
    }                                                                         \
  }

#define QKT(scv, bufi)                                                        \
  {                                                                           \
    _Pragma("unroll")                                                         \
    for (int f = 0; f < 2; ++f) {                                             \
      _Pragma("unroll")                                                       \
      for (int ks = 0; ks < 4; ++ks) {                                        \
        int cc = ((2 * ks + h) ^ rsw) * 8;                                    \
        f16x8 kv = *(const f16x8*)&sK[bufi][f * 32 + cq][cc];                 \
        scv[f] = mfma32(kv, qh_[ks], scv[f]);                                 \
        scv[f] = mfma32(kv, ql_[ks], scv[f]);                                 \
      }                                                                       \
    }                                                                         \
  }

#define PVT(bufi)                                                             \
  {                                                                           \
    _Pragma("unroll")                                                         \
    for (int ks = 0; ks < 4; ++ks) {                                          \
      _Pragma("unroll")                                                       \
      for (int df = 0; df < 2; ++df) {                                        \
        int cc = ((2 * ks + h) ^ rsw) * 8;                                    \
        f16x8 vf = *(const f16x8*)&sV[bufi][df * 32 + cq][cc];                \
        O[df] = mfma32(vf, pf[ks], O[df]);                                    \
      }                                                                       \
    }                                                                         \
  }

#define PFBUILD(scv)                                                          \
  {                                                                           \
    _Pragma("unroll")                                                         \
    for (int f = 0; f < 2; ++f) {                                             \
      _Pragma("unroll")                                                       \
      for (int ksl = 0; ksl < 2; ++ksl) {                                     \
        int b0 = 8 * ksl;                                                     \
        int a1 = pkrtz(scv[f][b0 + 0], scv[f][b0 + 1]);                       \
        int b1 = pkrtz(scv[f][b0 + 4], scv[f][b0 + 5]);                       \
        int2v r1 = __builtin_amdgcn_permlane32_swap(a1, b1, false, false);    \
        int a2 = pkrtz(scv[f][b0 + 2], scv[f][b0 + 3]);                       \
        int b2 = pkrtz(scv[f][b0 + 6], scv[f][b0 + 7]);                       \
        int2v r2 = __builtin_amdgcn_permlane32_swap(a2, b2, false, false);    \
        int4v wd;                                                             \
        wd[0] = r1[0]; wd[1] = r2[0]; wd[2] = r1[1]; wd[3] = r2[1];           \
        pf[2 * f + ksl] = __builtin_bit_cast(f16x8, wd);                      \
      }                                                                       \
    }                                                                         \
  }

#define MAXTREE(pm, scv)                                                      \
  {                                                                           \
    float t4[4];                                                              \
    _Pragma("unroll")                                                         \
    for (int i = 0; i < 4; ++i) {                                             \
      float a = fmaxf(fmaxf(scv[0][i], scv[0][i + 4]),                        \
                      fmaxf(scv[0][i + 8], scv[0][i + 12]));                  \
      float b = fmaxf(fmaxf(scv[1][i], scv[1][i + 4]),                        \
                      fmaxf(scv[1][i + 8], scv[1][i + 12]));                  \
      t4[i] = fmaxf(a, b);                                                    \
    }                                                                         \
    pm = fmaxf(fmaxf(t4[0], t4[1]), fmaxf(t4[2], t4[3]));                     \
    pm = fmaxf(pm, __shfl_xor(pm, 32));                                       \
  }

#define ROWSUM(rs, scv)                                                       \
  {                                                                           \
    float rs0 = 0.f, rs1 = 0.f, rs2 = 0.f, rs3 = 0.f;                         \
    _Pragma("unroll")                                                         \
    for (int f = 0; f < 2; ++f) {                                             \
      _Pragma("unroll")                                                       \
      for (int r4 = 0; r4 < 4; ++r4) {                                        \
        rs0 += scv[f][4 * r4 + 0];                                            \
        rs1 += scv[f][4 * r4 + 1];                                            \
        rs2 += scv[f][4 * r4 + 2];                                            \
        rs3 += scv[f][4 * r4 + 3];                                            \
      }                                                                       \
    }                                                                         \
    rs = (rs0 + rs1) + (rs2 + rs3);                                           \
    rs += __shfl_xor(rs, 32);                                                 \
  }

  // ---- prologue: chunk 0 (exact max path)
  int bc = 0, bn = 1, bs = 2;
  STAGE(0, 0);
  asm volatile("s_waitcnt vmcnt(0)" ::: "memory");
  __builtin_amdgcn_sched_barrier(0);
  __builtin_amdgcn_s_barrier();
  STAGE(1, 64);
  {
    f32x16 sc[2] = {};
    QKT(sc, 0);
    float pm;
    MAXTREE(pm, sc);
    m_run = pm;
#pragma unroll
    for (int f = 0; f < 2; ++f)
#pragma unroll
      for (int r = 0; r < 16; ++r)
        sc[f][r] = __builtin_amdgcn_exp2f(sc[f][r] - pm);
    float rs;
    ROWSUM(rs, sc);
    l_run = rs;
    PFBUILD(sc);
  }

  // ---- main pipeline: iter t does QK(t+1), STAGE(t+2), softmax(t+1), PV(t)
  for (int t = 0; t < 15; ++t) {
    asm volatile("s_waitcnt vmcnt(0)" ::: "memory");   // own STAGE(t+1) landed
    __builtin_amdgcn_sched_barrier(0);
    __builtin_amdgcn_s_barrier();                      // all waves' t+1 ready

    f32x16 sc[2];
#pragma unroll
    for (int f = 0; f < 2; ++f)
#pragma unroll
      for (int r = 0; r < 16; ++r) sc[f][r] = -m_run;
    __builtin_amdgcn_s_setprio(1);
    QKT(sc, bn);
    __builtin_amdgcn_s_setprio(0);
    if (t < 14) STAGE(bs, (t + 2) * 64);

    // speculative exp (vs running m); independent of PV(t)
#pragma unroll
    for (int f = 0; f < 2; ++f)
#pragma unroll
      for (int r = 0; r < 16; ++r)
        sc[f][r] = __builtin_amdgcn_exp2f(sc[f][r]);
    float pm;
    MAXTREE(pm, sc);
    bool trig = __any(pm > 2048.f);
    float scl = 1.f;
    if (trig) {
      float pmx = fmaxf(pm, 1.0f);
      scl = 1.0f / pmx;
      m_run += __builtin_amdgcn_logf(pmx);     // v_log_f32 = log2 (exp2 domain)
#pragma unroll
      for (int f = 0; f < 2; ++f)
#pragma unroll
        for (int r = 0; r < 16; ++r) sc[f][r] *= scl;
    }

    // PV(t): consumes pf (chunk t, old scale) -> O is old-scale thru t
    __builtin_amdgcn_s_setprio(1);
    PVT(bc);
    __builtin_amdgcn_s_setprio(0);

    if (trig) {
      l_run *= scl;
#pragma unroll
      for (int df = 0; df < 2; ++df)
#pragma unroll
        for (int i = 0; i < 16; ++i) O[df][i] *= scl;
    }
    float rs;
    ROWSUM(rs, sc);
    l_run += rs;
    PFBUILD(sc);
    int tmp = bc; bc = bn; bn = bs; bs = tmp;          // rotate buffers
  }
  // ---- last PV (chunk 15; synced at iter-14's barrier)
  PVT(bc);

  // ---- epilogue: relu(O/l) -> fp32 [B,S,E]
  float inv = 1.0f / l_run;
  int s = q0 + cq;
  float* orow = out + ((size_t)bb * S_ + s) * E_ + hd * 64;
#pragma unroll
  for (int df = 0; df < 2; ++df)
#pragma unroll
    for (int g = 0; g < 4; ++g) {
      f32x4 vv;
#pragma unroll
      for (int j = 0; j < 4; ++j)
        vv[j] = fmaxf(O[df][4 * g + j] * inv, 0.f);
      *(f32x4*)&orow[df * 32 + 8 * g + 4 * h] = vv;
    }
}

// ---------------------------------------------------------------------------
// Launcher. Workspace ~86 MB:
//  Wq,Wk,Wv 3x2MB @0; Xf @6M; Qh @22M; Ql @38M; Kf @54M; Vt @70M
// ---------------------------------------------------------------------------
extern "C" void kernel_launch(void* const* d_in, const int* in_sizes, int n_in,
                              void* d_out, int out_size, void* d_ws, size_t ws_size,
                              hipStream_t stream) {
  const float* X  = (const float*)d_in[0];
  const float* Wq = (const float*)d_in[1];
  const float* Wk = (const float*)d_in[2];
  const float* Wv = (const float*)d_in[3];
  float* out = (float*)d_out;
  char* ws = (char*)d_ws;

  const size_t WSZ = (size_t)E_ * E_ * sizeof(f16);   // 2 MB
  const size_t QSZ = (size_t)M_ * E_ * sizeof(f16);   // 16 MB
  f16* Wqf = (f16*)(ws);
  f16* Wkf = (f16*)(ws + WSZ);
  f16* Wvf = (f16*)(ws + 2 * WSZ);
  char* p = ws + 3 * WSZ;
  f16* Xf = (f16*)(p);
  f16* Qh = (f16*)(p + QSZ);
  f16* Ql = (f16*)(p + 2 * QSZ);
  f16* Kf = (f16*)(p + 3 * QSZ);
  f16* Vt = (f16*)(p + 4 * QSZ);

  presplit_kernel<<<4096, 256, 0, stream>>>(X, Xf);
  wt_conv3_kernel<<<dim3(16, 16, 3), dim3(64, 8), 0, stream>>>(
      Wq, Wk, Wv, Wqf, Wkf, Wvf);

  gemm_qkv_kernel<<<1536, 256, 0, stream>>>(
      Xf, Wqf, Wkf, Wvf, Qh, Ql, Kf, Vt);

  attn_kernel<<<1024, 256, 0, stream>>>(Qh, Ql, Kf, Vt, out);
}

// Round 11
// 132.661 us; speedup vs baseline: 1.4509x; 1.1078x over previous
//
#include <hip/hip_runtime.h>
#include <cstdint>
#include <cstddef>

#define B_ 8
#define S_ 1024
#define E_ 1024
#define H_ 16
#define D_ 64
#define M_ (B_*S_)

typedef _Float16 f16;
typedef __attribute__((ext_vector_type(8))) _Float16 f16x8;
typedef __attribute__((ext_vector_type(4))) _Float16 f16x4;
typedef __attribute__((ext_vector_type(4))) float  f32x4;
typedef __attribute__((ext_vector_type(16))) float f32x16;
typedef __attribute__((ext_vector_type(4))) int    int4v;
typedef __attribute__((ext_vector_type(2))) int    int2v;

__device__ __forceinline__ f32x4 mfma16(f16x8 a, f16x8 b, f32x4 c) {
  return __builtin_amdgcn_mfma_f32_16x16x32_f16(a, b, c, 0, 0, 0);
}
__device__ __forceinline__ f32x16 mfma32(f16x8 a, f16x8 b, f32x16 c) {
  return __builtin_amdgcn_mfma_f32_32x32x16_f16(a, b, c, 0, 0, 0);
}
__device__ __forceinline__ void gll16(const f16* g, f16* l) {
  __builtin_amdgcn_global_load_lds(
      (const __attribute__((address_space(1))) void*)g,
      (__attribute__((address_space(3))) void*)l, 16, 0, 0);
}
__device__ __forceinline__ int pkrtz(float lo, float hi) {
  return __builtin_bit_cast(int, __builtin_amdgcn_cvt_pkrtz(lo, hi));
}

// ---------------------------------------------------------------------------
// X fp32 -> fp16
// ---------------------------------------------------------------------------
__global__ __launch_bounds__(256) void presplit_kernel(
    const float* __restrict__ X, f16* __restrict__ Xf) {
  size_t i = ((size_t)blockIdx.x * 256 + threadIdx.x) * 8;
  f32x4 v0 = *(const f32x4*)&X[i];
  f32x4 v1 = *(const f32x4*)&X[i + 4];
  f16x8 hv;
#pragma unroll
  for (int j = 0; j < 4; ++j) {
    hv[j] = (f16)v0[j];
    hv[j + 4] = (f16)v1[j];
  }
  *(f16x8*)&Xf[i] = hv;
}

// ---------------------------------------------------------------------------
// Transpose + convert weights -> single fp16, [f][e] layout.
// W_Q pre-scaled by log2(e) (softmax runs in exp2 domain).
// ---------------------------------------------------------------------------
__global__ __launch_bounds__(512) void wt_conv3_kernel(
    const float* __restrict__ Wq, const float* __restrict__ Wk,
    const float* __restrict__ Wv, f16* __restrict__ oq, f16* __restrict__ ok,
    f16* __restrict__ ov) {
  const float* W = blockIdx.z == 0 ? Wq : (blockIdx.z == 1 ? Wk : Wv);
  f16* o = blockIdx.z == 0 ? oq : (blockIdx.z == 1 ? ok : ov);
  const float scl = blockIdx.z == 0 ? 1.4426950408889634f : 1.0f;
  __shared__ float t[64][65];
  const int f0 = blockIdx.x * 64, e0 = blockIdx.y * 64;
  const int tx = threadIdx.x, ty = threadIdx.y;
#pragma unroll
  for (int j = 0; j < 8; ++j)
    t[ty + 8 * j][tx] = W[(size_t)(e0 + ty + 8 * j) * E_ + f0 + tx];
  __syncthreads();
#pragma unroll
  for (int j = 0; j < 8; ++j)
    o[(size_t)(f0 + ty + 8 * j) * E_ + e0 + tx] =
        (f16)(t[tx][ty + 8 * j] * scl);
}

// ---------------------------------------------------------------------------
// Fused QKV GEMM: O = X(f16) * W(f16).  All outputs single fp16:
// z: 0-7 = Q ([B,H,S,D], log2e-scaled), 8-15 = K ([B,H,S,D]),
//    16-23 = V (transposed [B,H,D,S]).
// ---------------------------------------------------------------------------
__global__ __launch_bounds__(256) void gemm_qkv_kernel(
    const f16* __restrict__ Xf,
    const f16* __restrict__ Wq, const f16* __restrict__ Wk,
    const f16* __restrict__ Wv,
    f16* __restrict__ Qf, f16* __restrict__ Kf, f16* __restrict__ Vt) {
  __shared__ f16 sA[128][64], sB[128][64];   // 32 KB
  const int bid = blockIdx.x;
  const int xcd = bid & 7, idx = bid >> 3;   // idx in [0,192)
  const int mb = xcd * 8 + idx / 24;         // [0,64)
  const int nb = idx % 24;
  const int z = nb >> 3;
  const int n0 = (nb & 7) * 128, m0 = mb * 128;
  const f16* __restrict__ Bt = z == 0 ? Wq : (z == 1 ? Wk : Wv);
  const int tid = threadIdx.x;
  const int lane = tid & 63, w = tid >> 6;
  const int wm = (w >> 1) * 64, wn = (w & 1) * 64;
  const int fr = lane & 15, fg = lane >> 4;
  f32x4 acc[4][4] = {};
  for (int k0 = 0; k0 < E_; k0 += 64) {
#pragma unroll
    for (int i = 0; i < 4; ++i) {
      int ci = tid + i * 256;
      int r = ci >> 3, cl = ci & 7;
      int cs = (cl ^ (r & 7)) * 8;       // pre-swizzled global source column
      gll16(Xf + (size_t)(m0 + r) * E_ + k0 + cs, &sA[0][0] + ci * 8);
      gll16(Bt + (size_t)(n0 + r) * E_ + k0 + cs, &sB[0][0] + ci * 8);
    }
    __syncthreads();
#pragma unroll
    for (int kh2 = 0; kh2 < 2; ++kh2) {
      f16x8 ah[4];
#pragma unroll
      for (int mi = 0; mi < 4; ++mi) {
        int rA = wm + mi * 16 + fr;
        ah[mi] = *(const f16x8*)&sA[rA][(((kh2 * 4 + fg) ^ (rA & 7))) * 8];
      }
#pragma unroll
      for (int ni = 0; ni < 4; ++ni) {
        int rB = wn + ni * 16 + fr;
        f16x8 bh = *(const f16x8*)&sB[rB][(((kh2 * 4 + fg) ^ (rB & 7))) * 8];
#pragma unroll
        for (int mi = 0; mi < 4; ++mi)
          acc[mi][ni] = mfma16(ah[mi], bh, acc[mi][ni]);
      }
    }
    __syncthreads();
  }
  if (z < 2) {
    f16* Of = z == 0 ? Qf : Kf;
#pragma unroll
    for (int mi = 0; mi < 4; ++mi)
#pragma unroll
      for (int ni = 0; ni < 4; ++ni)
#pragma unroll
        for (int r = 0; r < 4; ++r) {
          int row = m0 + wm + mi * 16 + (lane >> 4) * 4 + r;
          int col = n0 + wn + ni * 16 + fr;
          int bb = row >> 10, s = row & 1023;
          int hd = col >> 6, d = col & 63;
          Of[((size_t)(bb * H_ + hd) * S_ + s) * D_ + d] = (f16)acc[mi][ni][r];
        }
  } else {
#pragma unroll
    for (int mi = 0; mi < 4; ++mi)
#pragma unroll
      for (int ni = 0; ni < 4; ++ni) {
        int row = m0 + wm + mi * 16 + (lane >> 4) * 4;
        int col = n0 + wn + ni * 16 + fr;
        int bb = row >> 10, s = row & 1023;
        int hd = col >> 6, d = col & 63;
        f16x4 p;
#pragma unroll
        for (int r = 0; r < 4; ++r) p[r] = (f16)acc[mi][ni][r];
        *(f16x4*)&Vt[((size_t)(bb * H_ + hd) * D_ + d) * S_ + s] = p;
      }
  }
}

// ---------------------------------------------------------------------------
// Flash attention + ReLU.  Round-11 = round-10 structure + EXACT chunk-0
// prologue (round-10 failure: m_run=30 init -> exp2(s-30) with s up to ~160
// log2-units overflows f32 -> Inf*0=NaN -> zeroed rows, absmax 4.78).
// m_run = exact chunk-0 row max; later chunks overflow only on a >128
// log2-unit jump (~7 sigma, negligible) and the 2^11 trigger rescales first.
// - 1-term fp16 QK^T; MFMA rowsum (Ol); 2-phase LDS (32KB), STAGE(t+1) at
//   iter top, vmcnt(0)+barrier at iter end; 4 blocks/CU (grid 1024).
// ---------------------------------------------------------------------------
__global__ __launch_bounds__(256, 4) void attn_kernel(
    const f16* __restrict__ Qf, const f16* __restrict__ Kf,
    const f16* __restrict__ Vt, float* __restrict__ out) {
  __shared__ f16 sK[2][64][64], sV[2][64][64];   // 32 KB
  const int bid = blockIdx.x;
  const int bh = (bid & 7) * 16 + (bid >> 6);    // 8 qb of one bh on one XCD
  const int qb = (bid >> 3) & 7;
  const int hd = bh & 15, bb = bh >> 4;
  const int tid = threadIdx.x;
  const int lane = tid & 63, w = tid >> 6;
  const int cq = lane & 31, h = lane >> 5;
  const int rsw = cq & 7;
  const size_t base = (size_t)bh * (S_ * D_);
  const f16* Qf_p = Qf + base;
  const f16* Kf_p = Kf + base;
  const f16* Vt_p = Vt + base;
  const int q0 = qb * 128 + w * 32;

  f16x8 qh_[4];
#pragma unroll
  for (int ks = 0; ks < 4; ++ks)
    qh_[ks] = *(const f16x8*)&Qf_p[(size_t)(q0 + cq) * D_ + ks * 16 + 8 * h];

  f16x8 ones;
#pragma unroll
  for (int j = 0; j < 8; ++j) ones[j] = (f16)1.0f;

  float m_run;
  f32x16 O[2] = {}, Ol = {};     // Ol: all-ones-A mfma rowsum (l = Ol[0])
  f16x8 pf[4];

#define STAGE(buf, kb)                                                        \
  {                                                                           \
    _Pragma("unroll")                                                         \
    for (int half = 0; half < 2; ++half) {                                    \
      int ci = tid + half * 256;                                              \
      int row = ci >> 3, cl = ci & 7;                                         \
      int cs = cl ^ (row & 7);                                                \
      gll16(Kf_p + (size_t)((kb) + row) * D_ + cs * 8, &sK[buf][0][0] + ci * 8); \
      gll16(Vt_p + (size_t)row * S_ + (kb) + cs * 8, &sV[buf][0][0] + ci * 8);   \
    }                                                                         \
  }

#define QKT(scv, bufi)                                                        \
  {                                                                           \
    _Pragma("unroll")                                                         \
    for (int f = 0; f < 2; ++f) {                                             \
      _Pragma("unroll")                                                       \
      for (int ks = 0; ks < 4; ++ks) {                                        \
        int cc = ((2 * ks + h) ^ rsw) * 8;                                    \
        f16x8 kv = *(const f16x8*)&sK[bufi][f * 32 + cq][cc];                 \
        scv[f] = mfma32(kv, qh_[ks], scv[f]);                                 \
      }                                                                       \
    }                                                                         \
  }

#define MAXTREE(pm, scv)                                                      \
  {                                                                           \
    float t4[4];                                                              \
    _Pragma("unroll")                                                         \
    for (int i = 0; i < 4; ++i) {                                             \
      float a = fmaxf(fmaxf(scv[0][i], scv[0][i + 4]),                        \
                      fmaxf(scv[0][i + 8], scv[0][i + 12]));                  \
      float b = fmaxf(fmaxf(scv[1][i], scv[1][i + 4]),                        \
                      fmaxf(scv[1][i + 8], scv[1][i + 12]));                  \
      t4[i] = fmaxf(a, b);                                                    \
    }                                                                         \
    pm = fmaxf(fmaxf(t4[0], t4[1]), fmaxf(t4[2], t4[3]));                     \
    pm = fmaxf(pm, __shfl_xor(pm, 32));                                       \
  }

#define PFBUILD(scv)                                                          \
  {                                                                           \
    _Pragma("unroll")                                                         \
    for (int f = 0; f < 2; ++f) {                                             \
      _Pragma("unroll")                                                       \
      for (int ksl = 0; ksl < 2; ++ksl) {                                     \
        int b0 = 8 * ksl;                                                     \
        int a1 = pkrtz(scv[f][b0 + 0], scv[f][b0 + 1]);                       \
        int b1 = pkrtz(scv[f][b0 + 4], scv[f][b0 + 5]);                       \
        int2v r1 = __builtin_amdgcn_permlane32_swap(a1, b1, false, false);    \
        int a2 = pkrtz(scv[f][b0 + 2], scv[f][b0 + 3]);                       \
        int b2 = pkrtz(scv[f][b0 + 6], scv[f][b0 + 7]);                       \
        int2v r2 = __builtin_amdgcn_permlane32_swap(a2, b2, false, false);    \
        int4v wd;                                                             \
        wd[0] = r1[0]; wd[1] = r2[0]; wd[2] = r1[1]; wd[3] = r2[1];           \
        pf[2 * f + ksl] = __builtin_bit_cast(f16x8, wd);                      \
      }                                                                       \
    }                                                                         \
  }

#define PVT(bufi)                                                             \
  {                                                                           \
    _Pragma("unroll")                                                         \
    for (int ks = 0; ks < 4; ++ks) {                                          \
      int cc = ((2 * ks + h) ^ rsw) * 8;                                      \
      _Pragma("unroll")                                                       \
      for (int df = 0; df < 2; ++df) {                                        \
        f16x8 vf = *(const f16x8*)&sV[bufi][df * 32 + cq][cc];                \
        O[df] = mfma32(vf, pf[ks], O[df]);                                    \
      }                                                                       \
      Ol = mfma32(ones, pf[ks], Ol);                                          \
    }                                                                         \
  }

  // ---- prologue: stage + compute chunk 0 with EXACT max (overflow-safe)
  STAGE(0, 0);
  asm volatile("s_waitcnt vmcnt(0)" ::: "memory");
  __builtin_amdgcn_sched_barrier(0);
  __builtin_amdgcn_s_barrier();
  STAGE(1, 64);                        // prefetch chunk 1 under chunk-0 work
  {
    f32x16 sc[2] = {};
    __builtin_amdgcn_s_setprio(1);
    QKT(sc, 0);
    __builtin_amdgcn_s_setprio(0);
    float pm;
    MAXTREE(pm, sc);
    m_run = pm;
#pragma unroll
    for (int f = 0; f < 2; ++f)
#pragma unroll
      for (int r = 0; r < 16; ++r)
        sc[f][r] = __builtin_amdgcn_exp2f(sc[f][r] - pm);
    PFBUILD(sc);
    __builtin_amdgcn_s_setprio(1);
    PVT(0);
    __builtin_amdgcn_s_setprio(0);
  }
  asm volatile("s_waitcnt vmcnt(0)" ::: "memory");
  __builtin_amdgcn_sched_barrier(0);
  __builtin_amdgcn_s_barrier();

  // ---- main loop, chunks 1..15: spec-exp + rare exact rescale
  for (int t = 1; t < 16; ++t) {
    const int cur = t & 1;
    if (t < 15) STAGE(cur ^ 1, (t + 1) * 64);   // hides under compute(t)

    f32x16 sc[2];
#pragma unroll
    for (int f = 0; f < 2; ++f)
#pragma unroll
      for (int r = 0; r < 16; ++r) sc[f][r] = -m_run;
    __builtin_amdgcn_s_setprio(1);
    QKT(sc, cur);
    __builtin_amdgcn_s_setprio(0);

#pragma unroll
    for (int f = 0; f < 2; ++f)
#pragma unroll
      for (int r = 0; r < 16; ++r)
        sc[f][r] = __builtin_amdgcn_exp2f(sc[f][r]);

    float pm;
    MAXTREE(pm, sc);
    if (__any(pm > 2048.f)) {
      float pmx = fmaxf(pm, 1.0f);
      float scl = 1.0f / pmx;
      m_run += __builtin_amdgcn_logf(pmx);   // v_log_f32 = log2
#pragma unroll
      for (int f = 0; f < 2; ++f)
#pragma unroll
        for (int r = 0; r < 16; ++r) sc[f][r] *= scl;
#pragma unroll
      for (int df = 0; df < 2; ++df)
#pragma unroll
        for (int i = 0; i < 16; ++i) O[df][i] *= scl;
#pragma unroll
      for (int i = 0; i < 16; ++i) Ol[i] *= scl;
    }

    PFBUILD(sc);
    __builtin_amdgcn_s_setprio(1);
    PVT(cur);
    __builtin_amdgcn_s_setprio(0);

    asm volatile("s_waitcnt vmcnt(0)" ::: "memory");
    __builtin_amdgcn_sched_barrier(0);
    __builtin_amdgcn_s_barrier();
  }

  // ---- epilogue: relu(O/l) -> fp32 [B,S,E];  l = Ol[0] (all rows equal)
  float inv = 1.0f / Ol[0];
  int s = q0 + cq;
  float* orow = out + ((size_t)bb * S_ + s) * E_ + hd * 64;
#pragma unroll
  for (int df = 0; df < 2; ++df)
#pragma unroll
    for (int g = 0; g < 4; ++g) {
      f32x4 vv;
#pragma unroll
      for (int j = 0; j < 4; ++j)
        vv[j] = fmaxf(O[df][4 * g + j] * inv, 0.f);
      *(f32x4*)&orow[df * 32 + 8 * g + 4 * h] = vv;
    }
}

// ---------------------------------------------------------------------------
// Launcher. Workspace ~70 MB:
//  Wq,Wk,Wv 3x2MB @0; Xf @6M; Qf @22M; Kf @38M; Vt @54M
// ---------------------------------------------------------------------------
extern "C" void kernel_launch(void* const* d_in, const int* in_sizes, int n_in,
                              void* d_out, int out_size, void* d_ws, size_t ws_size,
                              hipStream_t stream) {
  const float* X  = (const float*)d_in[0];
  const float* Wq = (const float*)d_in[1];
  const float* Wk = (const float*)d_in[2];
  const float* Wv = (const float*)d_in[3];
  float* out = (float*)d_out;
  char* ws = (char*)d_ws;

  const size_t WSZ = (size_t)E_ * E_ * sizeof(f16);   // 2 MB
  const size_t QSZ = (size_t)M_ * E_ * sizeof(f16);   // 16 MB
  f16* Wqf = (f16*)(ws);
  f16* Wkf = (f16*)(ws + WSZ);
  f16* Wvf = (f16*)(ws + 2 * WSZ);
  char* p = ws + 3 * WSZ;
  f16* Xf = (f16*)(p);
  f16* Qf = (f16*)(p + QSZ);
  f16* Kf = (f16*)(p + 2 * QSZ);
  f16* Vt = (f16*)(p + 3 * QSZ);

  presplit_kernel<<<4096, 256, 0, stream>>>(X, Xf);
  wt_conv3_kernel<<<dim3(16, 16, 3), dim3(64, 8), 0, stream>>>(
      Wq, Wk, Wv, Wqf, Wkf, Wvf);

  gemm_qkv_kernel<<<1536, 256, 0, stream>>>(
      Xf, Wqf, Wkf, Wvf, Qf, Kf, Vt);

  attn_kernel<<<1024, 256, 0, stream>>>(Qf, Kf, Vt, out);
}